// Round 8
// baseline (1085.921 us; speedup 1.0000x reference)
//
#include <hip/hip_runtime.h>
#include <math.h>

#define NB 16    // batch
#define SS 256   // spatial size (H = W = 256)
#define DV 32    // channels
#define MM 12    // w-dim (j) modes kept
#define MK 24    // h-dim (iy) modes kept (0..11 and 244..255)
#define LL 4     // layers
#define TWO_PI_N 0.024543692606170259679f   // 2*pi/256

// Workspace (floats):
//   h   : [NB][DV][SS][SS]            134 MB, in-place per layer
//   A   : [NB][MM][DV][SS(iy)][2]     12.6 MB  (row-DFT of h)
//   F   : [NB][MM][DV][MK][2]          1.2 MB  (mixed spectral coeffs, pre-scaled)
//   g   : [NB][SS(iy)][MM][DV][2]     12.6 MB  (per-row spectral coeffs)
//   twT : [SS][MM][2]                  24 KB   (cos, -sin) of 2*pi*ky*j/256
//   wT  : [LL][ci][co]                 16 KB   (transposed conv weights)

// --------------------------------------------- setup: twiddle table + weight^T
__global__ __launch_bounds__(256) void k_prep(const float* __restrict__ ws_w,
        float* __restrict__ twT, float* __restrict__ wT)
{
    int j = threadIdx.x;
    #pragma unroll
    for (int k = 0; k < MM; ++k) {
        float ang = TWO_PI_N * (float)((k * j) & 255);
        float s, c; sincosf(ang, &s, &c);
        twT[j * (MM * 2) + 2 * k]     = c;
        twT[j * (MM * 2) + 2 * k + 1] = -s;
    }
    for (int idx = threadIdx.x; idx < LL * DV * DV; idx += 256) {
        int l = idx >> 10, rem = idx & 1023, co = rem >> 5, ci = rem & 31;
        wT[(l * DV + ci) * DV + co] = ws_w[(l * DV + co) * DV + ci];
    }
}

// ---- fused row-DFT phase (runs after the block wrote its 4 h-rows).
// tid: half = tid>>7 (j in [half*128, half*128+128)), instance = tid&127,
// r = instance>>5 (row in block's 4-row tile), c = instance&31.
// j is wave-uniform -> twiddles come in via s_load. Cross-half reduction
// through a conflict-free [24][128] LDS transpose.
__device__ __forceinline__ void row_dft_phase(const float* __restrict__ h,
        const float* __restrict__ twT, float* __restrict__ A,
        float red[24][128], int b, int iy_base, int tid)
{
    int half = tid >> 7;
    int inst = tid & 127;
    int r = inst >> 5, c = inst & 31;
    int iy = iy_base + r;

    const float4* hr = (const float4*)(h + (((size_t)b * DV + c) * SS + iy) * SS
                                         + half * 128);
    float ar[MM], ai[MM];
    #pragma unroll
    for (int k = 0; k < MM; ++k) { ar[k] = 0.f; ai[k] = 0.f; }

    #pragma unroll 2
    for (int j4 = 0; j4 < 32; ++j4) {
        float4 v = hr[j4];
        float vv[4] = {v.x, v.y, v.z, v.w};
        #pragma unroll
        for (int u = 0; u < 4; ++u) {
            const float* twj = twT + (size_t)(half * 128 + 4 * j4 + u) * (MM * 2);
            float vu = vv[u];
            #pragma unroll
            for (int k = 0; k < 6; ++k) {
                ar[2*k]   += vu * twj[4*k];
                ai[2*k]   += vu * twj[4*k + 1];
                ar[2*k+1] += vu * twj[4*k + 2];
                ai[2*k+1] += vu * twj[4*k + 3];
            }
        }
    }

    if (half == 0) {
        #pragma unroll
        for (int k = 0; k < MM; ++k) {
            red[2*k][inst]     = ar[k];
            red[2*k + 1][inst] = ai[k];
        }
    }
    __syncthreads();
    if (half == 1) {
        #pragma unroll
        for (int k = 0; k < MM; ++k) {
            float2 val;
            val.x = ar[k] + red[2*k][inst];
            val.y = ai[k] + red[2*k + 1][inst];
            size_t o = ((((size_t)b * MM + k) * DV + c) * SS + iy) * 2;
            *(float2*)&A[o] = val;
        }
    }
}

// ---------------------------------------------------------------- lifting + A0
// grid = NB*64; block = 4 rows, one wave per row, 4 px/thread (float4).
__global__ __launch_bounds__(256, 2) void k_liftA(const float* __restrict__ x,
        const float* __restrict__ p_w, const float* __restrict__ p_b,
        float* __restrict__ h, const float* __restrict__ twT,
        float* __restrict__ A)
{
    __shared__ float red[24][128];
    int tid = threadIdx.x;
    int lane = tid & 63;
    int w = __builtin_amdgcn_readfirstlane(tid >> 6);
    int b  = blockIdx.x >> 6;
    int iy_base = (blockIdx.x & 63) << 2;
    int iy = iy_base + w;
    int j0 = lane << 2;

    float4 xv = *(const float4*)(x + ((size_t)(b * SS + iy)) * SS + j0);
    float gy = -1.f + 2.f * (float)iy * (1.f / 255.f);
    float4 gx;
    gx.x = -1.f + 2.f * (float)j0 * (1.f / 255.f);
    gx.y = gx.x + 2.f / 255.f; gx.z = gx.y + 2.f / 255.f; gx.w = gx.z + 2.f / 255.f;

    float* hb = h + ((size_t)b * DV * SS + iy) * SS + j0;
    #pragma unroll
    for (int c = 0; c < DV; ++c) {
        float w0 = p_w[3*c], w1 = p_w[3*c+1], w2 = p_w[3*c+2], bb = p_b[c];
        float4 v;
        v.x = w0 * xv.x + w1 * gy + w2 * gx.x + bb;
        v.y = w0 * xv.y + w1 * gy + w2 * gx.y + bb;
        v.z = w0 * xv.z + w1 * gy + w2 * gx.z + bb;
        v.w = w0 * xv.w + w1 * gy + w2 * gx.w + bb;
        *(float4*)(hb + (size_t)c * SS * SS) = v;
    }

    __threadfence_block();
    __syncthreads();                 // block's 4 rows visible to all threads
    row_dft_phase(h, twT, A, red, b, iy_base, tid);
}

// --------------------------- kx (iy) DFT + complex channel mix -> F (pre-scaled)
// (unchanged from round 7)
__global__ __launch_bounds__(256) void k_mix(const float* __restrict__ A,
        const float* __restrict__ w1r, const float* __restrict__ w1i,
        const float* __restrict__ w2r, const float* __restrict__ w2i,
        float* __restrict__ F, int l)
{
    __shared__ float twcs[SS * 2];
    __shared__ float Fin[DV][MK * 2 + 2];
    int tid = threadIdx.x;
    int b = blockIdx.x / MM, ky = blockIdx.x % MM;
    {
        float ang = TWO_PI_N * (float)tid;
        float s, c; sincosf(ang, &s, &c);
        twcs[2 * tid] = c; twcs[2 * tid + 1] = s;
    }
    __syncthreads();

    int c = tid >> 3, set = tid & 7;
    const float2* Ap = (const float2*)(A + ((((size_t)b * MM + ky) * DV + c) * SS) * 2);

    float fr[3], fi[3], pc[3], ps[3], sc[3], ssn[3];
    int f[3];
    #pragma unroll
    for (int k = 0; k < 3; ++k) {
        int m = set + 8 * k;
        f[k] = (m < MM) ? m : (232 + m);
        sc[k] = twcs[2 * f[k]]; ssn[k] = twcs[2 * f[k] + 1];
        fr[k] = fi[k] = 0.f; pc[k] = 1.f; ps[k] = 0.f;
    }
    for (int iy = 0; iy < SS; ++iy) {
        if ((iy & 63) == 0) {
            #pragma unroll
            for (int k = 0; k < 3; ++k) {
                int t = (f[k] * iy) & 255;
                pc[k] = twcs[2 * t]; ps[k] = twcs[2 * t + 1];
            }
        }
        float2 a = Ap[iy];
        #pragma unroll
        for (int k = 0; k < 3; ++k) {
            fr[k] += a.x * pc[k] + a.y * ps[k];
            fi[k] += a.y * pc[k] - a.x * ps[k];
            float np = pc[k] * sc[k] - ps[k] * ssn[k];
            float nq = pc[k] * ssn[k] + ps[k] * sc[k];
            pc[k] = np; ps[k] = nq;
        }
    }
    #pragma unroll
    for (int k = 0; k < 3; ++k) {
        int m = set + 8 * k;
        Fin[c][2 * m] = fr[k]; Fin[c][2 * m + 1] = fi[k];
    }
    __syncthreads();

    int o = c;
    float scale = ((ky == 0) ? 1.0f : 2.0f) * (1.0f / 65536.0f);
    #pragma unroll
    for (int k = 0; k < 3; ++k) {
        int m = set + 8 * k;
        const float* Wr; const float* Wi; int xm;
        if (m < MM) { Wr = w1r; Wi = w1i; xm = m; }
        else        { Wr = w2r; Wi = w2i; xm = m - MM; }
        float orr = 0.f, oii = 0.f;
        for (int i = 0; i < DV; ++i) {
            float gr = Fin[i][2 * m], gi = Fin[i][2 * m + 1];
            size_t wi = ((size_t)(l * DV + i) * DV + o) * (MM * MM) + xm * MM + ky;
            float wr = Wr[wi], wim = Wi[wi];
            orr += gr * wr - gi * wim;
            oii += gr * wim + gi * wr;
        }
        size_t off = ((((size_t)b * MM + ky) * DV + o) * MK + m) * 2;
        F[off] = orr * scale; F[off + 1] = oii * scale;
    }
}

// -------------------- inverse iy-DFT: F -> g[b][iy][ky][co][2]
// (unchanged from round 7)
__global__ __launch_bounds__(384) void k_inv1(const float* __restrict__ F,
        float* __restrict__ g)
{
    __shared__ float itw[MK * 2];
    int tid = threadIdx.x;
    int b = blockIdx.x >> 8, iy = blockIdx.x & 255;
    if (tid < MK) {
        int f = (tid < MM) ? tid : (232 + tid);
        float ang = TWO_PI_N * (float)((f * iy) & 255);
        float s, c; sincosf(ang, &s, &c);
        itw[2 * tid] = c; itw[2 * tid + 1] = s;
    }
    __syncthreads();

    int ky = tid >> 5, co = tid & 31;
    const float2* Fp = (const float2*)(F + ((((size_t)b * MM + ky) * DV + co) * MK) * 2);
    float gr = 0.f, gi = 0.f;
    #pragma unroll
    for (int m = 0; m < MK; ++m) {
        float2 fv = Fp[m];
        float ic = itw[2 * m], is = itw[2 * m + 1];
        gr += fv.x * ic - fv.y * is;
        gi += fv.x * is + fv.y * ic;
    }
    size_t o = (((size_t)(b * SS + iy)) * MM + ky) * (DV * 2) + 2 * co;
    g[o] = gr; g[o + 1] = gi;
}

// ---- pointwise core: acc[co] = conv1x1(h) + invDFT(g) for 4 px (one wave/row)
__device__ __forceinline__ void pt_core(const float* __restrict__ hb,
        const float* __restrict__ wt, const float* __restrict__ wsb,
        const float* __restrict__ gp, int j0, float4 acc[DV])
{
    #pragma unroll
    for (int co = 0; co < DV; ++co) {
        float bv = wsb[co];
        acc[co].x = bv; acc[co].y = bv; acc[co].z = bv; acc[co].w = bv;
    }

    #pragma unroll 4
    for (int ci = 0; ci < DV; ++ci) {
        float4 hv = *(const float4*)(hb + (size_t)ci * SS * SS);
        const float* wc = wt + ci * DV;              // 32 contiguous s_loads
        #pragma unroll
        for (int co = 0; co < DV; ++co) {
            float wv = wc[co];
            acc[co].x += wv * hv.x; acc[co].y += wv * hv.y;
            acc[co].z += wv * hv.z; acc[co].w += wv * hv.w;
        }
    }

    #pragma unroll 2
    for (int ky = 0; ky < MM; ++ky) {
        float s0, c0, st, ct;
        sincosf(TWO_PI_N * (float)((ky * j0) & 255), &s0, &c0);
        sincosf(TWO_PI_N * (float)ky, &st, &ct);
        float cs[4], sn[4];
        cs[0] = c0; sn[0] = s0;
        #pragma unroll
        for (int u = 1; u < 4; ++u) {
            float nc = cs[u-1] * ct - sn[u-1] * st;
            float ns = sn[u-1] * ct + cs[u-1] * st;
            cs[u] = nc; sn[u] = ns;
        }
        const float* Gk = gp + ky * (DV * 2);        // 64 contiguous s_loads
        #pragma unroll
        for (int co = 0; co < DV; ++co) {
            float gr = Gk[2 * co], gi = Gk[2 * co + 1];
            acc[co].x += gr * cs[0] - gi * sn[0];
            acc[co].y += gr * cs[1] - gi * sn[1];
            acc[co].z += gr * cs[2] - gi * sn[2];
            acc[co].w += gr * cs[3] - gi * sn[3];
        }
    }
}

// ----------------- layers 0..2: h = relu(conv + spectral), then fused row-DFT
__global__ __launch_bounds__(256, 2) void k_ptA(float* __restrict__ h,
        const float* __restrict__ g, const float* __restrict__ wT,
        const float* __restrict__ ws_b, const float* __restrict__ twT,
        float* __restrict__ A, int l)
{
    __shared__ float red[24][128];
    int tid = threadIdx.x;
    int lane = tid & 63;
    int w = __builtin_amdgcn_readfirstlane(tid >> 6);
    int b  = blockIdx.x >> 6;
    int iy_base = (blockIdx.x & 63) << 2;
    int iy = iy_base + w;
    int j0 = lane << 2;

    float* hb = h + ((size_t)b * DV * SS + iy) * SS + j0;
    const float* wt  = wT + (size_t)l * DV * DV;
    const float* wsb = ws_b + (size_t)l * DV;
    const float* gp  = g + ((size_t)(b * SS + iy)) * (MM * DV * 2);

    float4 acc[DV];
    pt_core(hb, wt, wsb, gp, j0, acc);

    #pragma unroll
    for (int co = 0; co < DV; ++co) {
        float4 v;
        v.x = fmaxf(acc[co].x, 0.f); v.y = fmaxf(acc[co].y, 0.f);
        v.z = fmaxf(acc[co].z, 0.f); v.w = fmaxf(acc[co].w, 0.f);
        *(float4*)(hb + (size_t)co * SS * SS) = v;
    }

    __threadfence_block();
    __syncthreads();                 // new rows visible block-wide
    row_dft_phase(h, twT, A, red, b, iy_base, tid);
}

// ----------------- last layer fused with projection (no relu, no row-DFT)
__global__ __launch_bounds__(256, 2) void k_final(const float* __restrict__ h,
        const float* __restrict__ g, const float* __restrict__ wT,
        const float* __restrict__ ws_b, const float* __restrict__ q_w,
        const float* __restrict__ q_b, float* __restrict__ out, int l)
{
    int tid = threadIdx.x;
    int lane = tid & 63;
    int w = __builtin_amdgcn_readfirstlane(tid >> 6);
    int b  = blockIdx.x >> 6;
    int iy = ((blockIdx.x & 63) << 2) + w;
    int j0 = lane << 2;

    const float* hb = h + ((size_t)b * DV * SS + iy) * SS + j0;
    const float* wt  = wT + (size_t)l * DV * DV;
    const float* wsb = ws_b + (size_t)l * DV;
    const float* gp  = g + ((size_t)(b * SS + iy)) * (MM * DV * 2);

    float4 acc[DV];
    pt_core(hb, wt, wsb, gp, j0, acc);

    float qb = q_b[0];
    float4 o4; o4.x = qb; o4.y = qb; o4.z = qb; o4.w = qb;
    #pragma unroll
    for (int co = 0; co < DV; ++co) {
        float qv = q_w[co];
        o4.x += qv * acc[co].x; o4.y += qv * acc[co].y;
        o4.z += qv * acc[co].z; o4.w += qv * acc[co].w;
    }
    *(float4*)(out + ((size_t)(b * SS + iy)) * SS + j0) = o4;
}

extern "C" void kernel_launch(void* const* d_in, const int* in_sizes, int n_in,
                              void* d_out, int out_size, void* d_ws, size_t ws_size,
                              hipStream_t stream)
{
    const float* x    = (const float*)d_in[0];
    const float* p_w  = (const float*)d_in[1];
    const float* p_b  = (const float*)d_in[2];
    const float* ws_w = (const float*)d_in[3];
    const float* ws_b = (const float*)d_in[4];
    const float* w1r  = (const float*)d_in[5];
    const float* w1i  = (const float*)d_in[6];
    const float* w2r  = (const float*)d_in[7];
    const float* w2i  = (const float*)d_in[8];
    const float* q_w  = (const float*)d_in[9];
    const float* q_b  = (const float*)d_in[10];
    float* out = (float*)d_out;

    float* h   = (float*)d_ws;
    float* A   = h + (size_t)NB * DV * SS * SS;
    float* F   = A + (size_t)NB * MM * DV * SS * 2;
    float* g   = F + (size_t)NB * MM * DV * MK * 2;
    float* twT = g + (size_t)NB * SS * MM * DV * 2;
    float* wT  = twT + (size_t)SS * MM * 2;

    dim3 blk(256);
    k_prep<<<1, blk, 0, stream>>>(ws_w, twT, wT);
    k_liftA<<<NB * 64, blk, 0, stream>>>(x, p_w, p_b, h, twT, A);
    for (int l = 0; l < LL; ++l) {
        k_mix<<<NB * MM, blk, 0, stream>>>(A, w1r, w1i, w2r, w2i, F, l);
        k_inv1<<<NB * SS, dim3(384), 0, stream>>>(F, g);
        if (l < LL - 1)
            k_ptA<<<NB * 64, blk, 0, stream>>>(h, g, wT, ws_b, twT, A, l);
        else
            k_final<<<NB * 64, blk, 0, stream>>>(h, g, wT, ws_b,
                                                 q_w, q_b, out, l);
    }
}

// Round 9
// 832.025 us; speedup vs baseline: 1.3052x; 1.3052x over previous
//
#include <hip/hip_runtime.h>
#include <math.h>

#define NB 16    // batch
#define SS 256   // spatial size (H = W = 256)
#define DV 32    // channels
#define MM 12    // w-dim (j) modes kept
#define MK 24    // h-dim (iy) modes kept (0..11 and 244..255)
#define LL 4     // layers
#define TWO_PI_N 0.024543692606170259679f   // 2*pi/256

// Workspace (floats):
//   h   : [NB][DV][SS][SS]            134 MB, in-place per layer
//   A   : [NB][MM][DV][SS(iy)][2]     12.6 MB  (row-DFT of h)
//   F   : [NB][MM][DV][MK][2]          1.2 MB  (mixed spectral coeffs, pre-scaled)
//   g   : [NB][SS(iy)][MM][DV][2]     12.6 MB  (per-row spectral coeffs)
//   Fin : [NB][MM][DV][MK][2]          1.2 MB  (iy-DFT of A, pre-mix)
//   twT : [SS][MM][2]                  24 KB   (cos, -sin) of 2*pi*ky*j/256
//   wT  : [LL][ci][co]                 16 KB   (transposed conv weights)

// --------------------------------------------- setup: twiddle table + weight^T
__global__ __launch_bounds__(256) void k_prep(const float* __restrict__ ws_w,
        float* __restrict__ twT, float* __restrict__ wT)
{
    int j = threadIdx.x;
    #pragma unroll
    for (int k = 0; k < MM; ++k) {
        float ang = TWO_PI_N * (float)((k * j) & 255);
        float s, c; sincosf(ang, &s, &c);
        twT[j * (MM * 2) + 2 * k]     = c;
        twT[j * (MM * 2) + 2 * k + 1] = -s;
    }
    for (int idx = threadIdx.x; idx < LL * DV * DV; idx += 256) {
        int l = idx >> 10, rem = idx & 1023, co = rem >> 5, ci = rem & 31;
        wT[(l * DV + ci) * DV + co] = ws_w[(l * DV + co) * DV + ci];
    }
}

// ---------------------------------------------------------------- lifting
// grid = NB*64; block = 4 rows, one wave per row, 4 px/thread (float4).
__global__ __launch_bounds__(256) void k_lift(const float* __restrict__ x,
        const float* __restrict__ p_w, const float* __restrict__ p_b,
        float* __restrict__ h)
{
    int tid = threadIdx.x;
    int lane = tid & 63;
    int w = __builtin_amdgcn_readfirstlane(tid >> 6);
    int b  = blockIdx.x >> 6;
    int iy = ((blockIdx.x & 63) << 2) + w;
    int j0 = lane << 2;

    float4 xv = *(const float4*)(x + ((size_t)(b * SS + iy)) * SS + j0);
    float gy = -1.f + 2.f * (float)iy * (1.f / 255.f);
    float4 gx;
    gx.x = -1.f + 2.f * (float)j0 * (1.f / 255.f);
    gx.y = gx.x + 2.f / 255.f; gx.z = gx.y + 2.f / 255.f; gx.w = gx.z + 2.f / 255.f;

    float* hb = h + ((size_t)b * DV * SS + iy) * SS + j0;
    #pragma unroll
    for (int c = 0; c < DV; ++c) {
        float w0 = p_w[3*c], w1 = p_w[3*c+1], w2 = p_w[3*c+2], bb = p_b[c];
        float4 v;
        v.x = w0 * xv.x + w1 * gy + w2 * gx.x + bb;
        v.y = w0 * xv.y + w1 * gy + w2 * gx.y + bb;
        v.z = w0 * xv.z + w1 * gy + w2 * gx.z + bb;
        v.w = w0 * xv.w + w1 * gy + w2 * gx.w + bb;
        *(float4*)(hb + (size_t)c * SS * SS) = v;
    }
}

// ------------------------------------------------- forward row (j) DFT, 12 modes
// block = (b,c); 512 threads: half = tid>>8 (wave-uniform), iy = tid&255.
// Each thread sums 128 j's (half a row); twiddles via s_load (uniform index);
// cross-half reduction through a conflict-free 24 KB LDS array.
__global__ __launch_bounds__(512, 4) void k_rowdft(const float* __restrict__ h,
        const float* __restrict__ twT, float* __restrict__ A)
{
    __shared__ float red[MM * 2][SS];   // 24 KB
    int tid = threadIdx.x;
    int iy = tid & 255;
    int half = __builtin_amdgcn_readfirstlane(tid >> 8);
    int b = blockIdx.x >> 5, c = blockIdx.x & 31;

    const float4* hr = (const float4*)(h + ((size_t)blockIdx.x * SS + iy) * SS
                                         + half * 128);
    float ar[MM], ai[MM];
    #pragma unroll
    for (int k = 0; k < MM; ++k) { ar[k] = 0.f; ai[k] = 0.f; }

    #pragma unroll 4
    for (int j4 = 0; j4 < 32; ++j4) {
        float4 v = hr[j4];
        float vv[4] = {v.x, v.y, v.z, v.w};
        #pragma unroll
        for (int u = 0; u < 4; ++u) {
            const float* twj = twT + (size_t)(half * 128 + 4 * j4 + u) * (MM * 2);
            float vu = vv[u];
            #pragma unroll
            for (int k = 0; k < 6; ++k) {
                ar[2*k]   += vu * twj[4*k];
                ai[2*k]   += vu * twj[4*k + 1];
                ar[2*k+1] += vu * twj[4*k + 2];
                ai[2*k+1] += vu * twj[4*k + 3];
            }
        }
    }

    if (half == 0) {
        #pragma unroll
        for (int k = 0; k < MM; ++k) {
            red[2*k][iy]     = ar[k];
            red[2*k + 1][iy] = ai[k];
        }
    }
    __syncthreads();
    if (half == 1) {
        #pragma unroll
        for (int ky = 0; ky < MM; ++ky) {
            float2 val;
            val.x = ar[ky] + red[2*ky][iy];
            val.y = ai[ky] + red[2*ky + 1][iy];
            size_t o = ((((size_t)b * MM + ky) * DV + c) * SS + iy) * 2;
            *(float2*)&A[o] = val;
        }
    }
}

// ------------------- iy-DFT of A -> Fin[b][ky][c][m][2]   (was k_mix phase 1)
// grid = (b*MM+ky)*4 + mg  (768 blocks). thread = (c, iy-chunk of 32), 6 modes.
// Register phasors anchored exactly; 8-lane shfl_xor reduce; predicated writes.
__global__ __launch_bounds__(256, 4) void k_coldft(const float* __restrict__ A,
        float* __restrict__ Fin)
{
    int blk = blockIdx.x;
    int mg = blk & 3;
    int bk = blk >> 2;                       // b*MM + ky
    int tid = threadIdx.x;
    int c = tid >> 3, ch = tid & 7;
    int iy0 = ch * 32;

    const float2* Ap = (const float2*)(A + ((size_t)bk * DV + c) * SS * 2);

    float fr[6], fi[6], pc[6], ps[6], sc[6], ssn[6];
    #pragma unroll
    for (int k = 0; k < 6; ++k) {
        int m = mg * 6 + k;
        int f = (m < MM) ? m : (232 + m);    // 244..255 for m >= 12
        float s, cc;
        sincosf(TWO_PI_N * (float)f, &s, &cc);
        sc[k] = cc; ssn[k] = s;              // step e^{+i dth} on (cos,sin) pair
        sincosf(TWO_PI_N * (float)((f * iy0) & 255), &s, &cc);
        pc[k] = cc; ps[k] = s;               // (cos th, sin th), th = f*iy0
        fr[k] = fi[k] = 0.f;
    }
    #pragma unroll 4
    for (int i = 0; i < 32; ++i) {
        float2 a = Ap[iy0 + i];
        #pragma unroll
        for (int k = 0; k < 6; ++k) {
            fr[k] += a.x * pc[k] + a.y * ps[k];   // A * e^{-i th}
            fi[k] += a.y * pc[k] - a.x * ps[k];
            float np = pc[k] * sc[k] - ps[k] * ssn[k];
            float nq = pc[k] * ssn[k] + ps[k] * sc[k];
            pc[k] = np; ps[k] = nq;
        }
    }
    // reduce over the 8 chunk lanes (tid low 3 bits -> adjacent lanes)
    #pragma unroll
    for (int m = 1; m < 8; m <<= 1) {
        #pragma unroll
        for (int k = 0; k < 6; ++k) {
            fr[k] += __shfl_xor(fr[k], m, 64);
            fi[k] += __shfl_xor(fi[k], m, 64);
        }
    }
    #pragma unroll
    for (int k = 0; k < 6; ++k) {
        if (ch == k) {
            int m = mg * 6 + k;
            size_t o = (((size_t)bk * DV + c) * MK + m) * 2;
            Fin[o] = fr[k]; Fin[o + 1] = fi[k];
        }
    }
}

// ------------------- channel mix: Fin -> F (pre-scaled)   (was k_mix phase 2)
__global__ __launch_bounds__(256) void k_mix2(const float* __restrict__ FinG,
        const float* __restrict__ w1r, const float* __restrict__ w1i,
        const float* __restrict__ w2r, const float* __restrict__ w2i,
        float* __restrict__ F, int l)
{
    __shared__ float Fin[DV][MK * 2 + 2];
    int tid = threadIdx.x;
    int b = blockIdx.x / MM, ky = blockIdx.x % MM;

    const float* Fs = FinG + ((size_t)(b * MM + ky)) * DV * MK * 2;
    for (int idx = tid; idx < DV * MK * 2; idx += 256) {
        int c = idx / (MK * 2), r = idx % (MK * 2);
        Fin[c][r] = Fs[idx];
    }
    __syncthreads();

    int o = tid >> 3, set = tid & 7;
    float scale = ((ky == 0) ? 1.0f : 2.0f) * (1.0f / 65536.0f);
    #pragma unroll
    for (int k = 0; k < 3; ++k) {
        int m = set + 8 * k;
        const float* Wr; const float* Wi; int xm;
        if (m < MM) { Wr = w1r; Wi = w1i; xm = m; }
        else        { Wr = w2r; Wi = w2i; xm = m - MM; }
        float orr = 0.f, oii = 0.f;
        for (int i = 0; i < DV; ++i) {
            float gr = Fin[i][2 * m], gi = Fin[i][2 * m + 1];
            size_t wi = ((size_t)(l * DV + i) * DV + o) * (MM * MM) + xm * MM + ky;
            float wr = Wr[wi], wim = Wi[wi];
            orr += gr * wr - gi * wim;
            oii += gr * wim + gi * wr;
        }
        size_t off = ((((size_t)b * MM + ky) * DV + o) * MK + m) * 2;
        F[off] = orr * scale; F[off + 1] = oii * scale;
    }
}

// -------------------- inverse iy-DFT: F -> g[b][iy][ky][co][2]
__global__ __launch_bounds__(384) void k_inv1(const float* __restrict__ F,
        float* __restrict__ g)
{
    __shared__ float itw[MK * 2];
    int tid = threadIdx.x;
    int b = blockIdx.x >> 8, iy = blockIdx.x & 255;
    if (tid < MK) {
        int f = (tid < MM) ? tid : (232 + tid);
        float ang = TWO_PI_N * (float)((f * iy) & 255);
        float s, c; sincosf(ang, &s, &c);
        itw[2 * tid] = c; itw[2 * tid + 1] = s;
    }
    __syncthreads();

    int ky = tid >> 5, co = tid & 31;
    const float2* Fp = (const float2*)(F + ((((size_t)b * MM + ky) * DV + co) * MK) * 2);
    float gr = 0.f, gi = 0.f;
    #pragma unroll
    for (int m = 0; m < MK; ++m) {
        float2 fv = Fp[m];
        float ic = itw[2 * m], is = itw[2 * m + 1];
        gr += fv.x * ic - fv.y * is;
        gi += fv.x * is + fv.y * ic;
    }
    size_t o = (((size_t)(b * SS + iy)) * MM + ky) * (DV * 2) + 2 * co;
    g[o] = gr; g[o + 1] = gi;
}

// ----------------- pointwise: h = relu(conv1x1(h) + invDFT(F)), in place.
// grid = NB*64; block = 4 rows, one WAVE per row, 4 px/thread (float4).
// No LDS, no barriers (proven round-7 structure).
template<int FINAL>
__global__ __launch_bounds__(256, 2) void k_pt(float* __restrict__ h,
        const float* __restrict__ g, const float* __restrict__ wT,
        const float* __restrict__ ws_b, const float* __restrict__ q_w,
        const float* __restrict__ q_b, float* __restrict__ out, int l)
{
    int tid = threadIdx.x;
    int lane = tid & 63;
    int w = __builtin_amdgcn_readfirstlane(tid >> 6);
    int b  = blockIdx.x >> 6;
    int iy = ((blockIdx.x & 63) << 2) + w;
    int j0 = lane << 2;

    float* hb = h + ((size_t)b * DV * SS + iy) * SS + j0;
    const float* wt  = wT + (size_t)l * DV * DV;     // [ci][co], uniform
    const float* wsb = ws_b + (size_t)l * DV;

    float4 acc[DV];
    #pragma unroll
    for (int co = 0; co < DV; ++co) {
        float bv = wsb[co];
        acc[co].x = bv; acc[co].y = bv; acc[co].z = bv; acc[co].w = bv;
    }

    #pragma unroll 4
    for (int ci = 0; ci < DV; ++ci) {
        float4 hv = *(const float4*)(hb + (size_t)ci * SS * SS);
        const float* wc = wt + ci * DV;              // 32 contiguous s_loads
        #pragma unroll
        for (int co = 0; co < DV; ++co) {
            float wv = wc[co];
            acc[co].x += wv * hv.x; acc[co].y += wv * hv.y;
            acc[co].z += wv * hv.z; acc[co].w += wv * hv.w;
        }
    }

    const float* gp = g + ((size_t)(b * SS + iy)) * (MM * DV * 2);  // uniform
    #pragma unroll 2
    for (int ky = 0; ky < MM; ++ky) {
        float s0, c0, st, ct;
        sincosf(TWO_PI_N * (float)((ky * j0) & 255), &s0, &c0);
        sincosf(TWO_PI_N * (float)ky, &st, &ct);
        float cs[4], sn[4];
        cs[0] = c0; sn[0] = s0;
        #pragma unroll
        for (int u = 1; u < 4; ++u) {
            float nc = cs[u-1] * ct - sn[u-1] * st;
            float ns = sn[u-1] * ct + cs[u-1] * st;
            cs[u] = nc; sn[u] = ns;
        }
        const float* Gk = gp + ky * (DV * 2);        // 64 contiguous s_loads
        #pragma unroll
        for (int co = 0; co < DV; ++co) {
            float gr = Gk[2 * co], gi = Gk[2 * co + 1];
            acc[co].x += gr * cs[0] - gi * sn[0];
            acc[co].y += gr * cs[1] - gi * sn[1];
            acc[co].z += gr * cs[2] - gi * sn[2];
            acc[co].w += gr * cs[3] - gi * sn[3];
        }
    }

    if (FINAL) {
        float qb = q_b[0];
        float4 o4; o4.x = qb; o4.y = qb; o4.z = qb; o4.w = qb;
        #pragma unroll
        for (int co = 0; co < DV; ++co) {
            float qv = q_w[co];
            o4.x += qv * acc[co].x; o4.y += qv * acc[co].y;
            o4.z += qv * acc[co].z; o4.w += qv * acc[co].w;
        }
        *(float4*)(out + ((size_t)(b * SS + iy)) * SS + j0) = o4;
    } else {
        #pragma unroll
        for (int co = 0; co < DV; ++co) {
            float4 v;
            v.x = fmaxf(acc[co].x, 0.f); v.y = fmaxf(acc[co].y, 0.f);
            v.z = fmaxf(acc[co].z, 0.f); v.w = fmaxf(acc[co].w, 0.f);
            *(float4*)(hb + (size_t)co * SS * SS) = v;
        }
    }
}

extern "C" void kernel_launch(void* const* d_in, const int* in_sizes, int n_in,
                              void* d_out, int out_size, void* d_ws, size_t ws_size,
                              hipStream_t stream)
{
    const float* x    = (const float*)d_in[0];
    const float* p_w  = (const float*)d_in[1];
    const float* p_b  = (const float*)d_in[2];
    const float* ws_w = (const float*)d_in[3];
    const float* ws_b = (const float*)d_in[4];
    const float* w1r  = (const float*)d_in[5];
    const float* w1i  = (const float*)d_in[6];
    const float* w2r  = (const float*)d_in[7];
    const float* w2i  = (const float*)d_in[8];
    const float* q_w  = (const float*)d_in[9];
    const float* q_b  = (const float*)d_in[10];
    float* out = (float*)d_out;

    float* h   = (float*)d_ws;
    float* A   = h   + (size_t)NB * DV * SS * SS;
    float* F   = A   + (size_t)NB * MM * DV * SS * 2;
    float* g   = F   + (size_t)NB * MM * DV * MK * 2;
    float* Fin = g   + (size_t)NB * SS * MM * DV * 2;
    float* twT = Fin + (size_t)NB * MM * DV * MK * 2;
    float* wT  = twT + (size_t)SS * MM * 2;

    dim3 blk(256);
    k_prep<<<1, blk, 0, stream>>>(ws_w, twT, wT);
    k_lift<<<NB * 64, blk, 0, stream>>>(x, p_w, p_b, h);
    for (int l = 0; l < LL; ++l) {
        k_rowdft<<<NB * DV, dim3(512), 0, stream>>>(h, twT, A);
        k_coldft<<<NB * MM * 4, blk, 0, stream>>>(A, Fin);
        k_mix2<<<NB * MM, blk, 0, stream>>>(Fin, w1r, w1i, w2r, w2i, F, l);
        k_inv1<<<NB * SS, dim3(384), 0, stream>>>(F, g);
        if (l < LL - 1)
            k_pt<0><<<NB * 64, blk, 0, stream>>>(h, g, wT, ws_b,
                                                 nullptr, nullptr, nullptr, l);
        else
            k_pt<1><<<NB * 64, blk, 0, stream>>>(h, g, wT, ws_b,
                                                 q_w, q_b, out, l);
    }
}

// Round 10
// 737.543 us; speedup vs baseline: 1.4723x; 1.1281x over previous
//
#include <hip/hip_runtime.h>
#include <math.h>

#define NB 16    // batch
#define SS 256   // spatial size (H = W = 256)
#define DV 32    // channels
#define MM 12    // w-dim (j) modes kept
#define MK 24    // h-dim (iy) modes kept (0..11 and 244..255)
#define LL 4     // layers
#define TWO_PI_N 0.024543692606170259679f   // 2*pi/256

// Workspace (floats):
//   h   : [NB][DV][SS][SS]            134 MB, in-place per layer
//   A   : [NB][MM][DV][SS(iy)][2]     12.6 MB  (row-DFT of h)
//   F   : [NB][MM][DV][MK][2]          1.2 MB  (mixed spectral coeffs, pre-scaled)
//   g   : [NB][SS(iy)][MM][DV][2]     12.6 MB  (per-row spectral coeffs)
//   twT : [SS][MM][2]                  24 KB   (cos, -sin) of 2*pi*ky*j/256  (fwd DFT)
//   wT  : [LL][ci][co]                 16 KB   (transposed conv weights)
//   tw2 : [MM][SS][2]                  24 KB   (cos, +sin)  (inverse j-DFT, coalesced)

// --------------------------------------------- setup: tables + weight^T
__global__ __launch_bounds__(256) void k_prep(const float* __restrict__ ws_w,
        float* __restrict__ twT, float* __restrict__ wT, float* __restrict__ tw2)
{
    int j = threadIdx.x;
    #pragma unroll
    for (int k = 0; k < MM; ++k) {
        float ang = TWO_PI_N * (float)((k * j) & 255);
        float s, c; sincosf(ang, &s, &c);
        twT[j * (MM * 2) + 2 * k]     = c;
        twT[j * (MM * 2) + 2 * k + 1] = -s;
        tw2[(k * SS + j) * 2]     = c;
        tw2[(k * SS + j) * 2 + 1] = s;
    }
    for (int idx = threadIdx.x; idx < LL * DV * DV; idx += 256) {
        int l = idx >> 10, rem = idx & 1023, co = rem >> 5, ci = rem & 31;
        wT[(l * DV + ci) * DV + co] = ws_w[(l * DV + co) * DV + ci];
    }
}

// ---------------------------------------------------------------- lifting
// grid = NB*64; block = 4 rows, one wave per row, 4 px/thread (float4).
__global__ __launch_bounds__(256) void k_lift(const float* __restrict__ x,
        const float* __restrict__ p_w, const float* __restrict__ p_b,
        float* __restrict__ h)
{
    int tid = threadIdx.x;
    int lane = tid & 63;
    int w = __builtin_amdgcn_readfirstlane(tid >> 6);
    int b  = blockIdx.x >> 6;
    int iy = ((blockIdx.x & 63) << 2) + w;
    int j0 = lane << 2;

    float4 xv = *(const float4*)(x + ((size_t)(b * SS + iy)) * SS + j0);
    float gy = -1.f + 2.f * (float)iy * (1.f / 255.f);
    float4 gx;
    gx.x = -1.f + 2.f * (float)j0 * (1.f / 255.f);
    gx.y = gx.x + 2.f / 255.f; gx.z = gx.y + 2.f / 255.f; gx.w = gx.z + 2.f / 255.f;

    float* hb = h + ((size_t)b * DV * SS + iy) * SS + j0;
    #pragma unroll
    for (int c = 0; c < DV; ++c) {
        float w0 = p_w[3*c], w1 = p_w[3*c+1], w2 = p_w[3*c+2], bb = p_b[c];
        float4 v;
        v.x = w0 * xv.x + w1 * gy + w2 * gx.x + bb;
        v.y = w0 * xv.y + w1 * gy + w2 * gx.y + bb;
        v.z = w0 * xv.z + w1 * gy + w2 * gx.z + bb;
        v.w = w0 * xv.w + w1 * gy + w2 * gx.w + bb;
        *(float4*)(hb + (size_t)c * SS * SS) = v;
    }
}

// ------------------------------------------------- forward row (j) DFT, 12 modes
// block = (b,c); 512 threads: half = tid>>8 (wave-uniform), iy = tid&255.
// (unchanged from round 9 — proven)
__global__ __launch_bounds__(512, 4) void k_rowdft(const float* __restrict__ h,
        const float* __restrict__ twT, float* __restrict__ A)
{
    __shared__ float red[MM * 2][SS];   // 24 KB
    int tid = threadIdx.x;
    int iy = tid & 255;
    int half = __builtin_amdgcn_readfirstlane(tid >> 8);
    int b = blockIdx.x >> 5, c = blockIdx.x & 31;

    const float4* hr = (const float4*)(h + ((size_t)blockIdx.x * SS + iy) * SS
                                         + half * 128);
    float ar[MM], ai[MM];
    #pragma unroll
    for (int k = 0; k < MM; ++k) { ar[k] = 0.f; ai[k] = 0.f; }

    #pragma unroll 4
    for (int j4 = 0; j4 < 32; ++j4) {
        float4 v = hr[j4];
        float vv[4] = {v.x, v.y, v.z, v.w};
        #pragma unroll
        for (int u = 0; u < 4; ++u) {
            const float* twj = twT + (size_t)(half * 128 + 4 * j4 + u) * (MM * 2);
            float vu = vv[u];
            #pragma unroll
            for (int k = 0; k < 6; ++k) {
                ar[2*k]   += vu * twj[4*k];
                ai[2*k]   += vu * twj[4*k + 1];
                ar[2*k+1] += vu * twj[4*k + 2];
                ai[2*k+1] += vu * twj[4*k + 3];
            }
        }
    }

    if (half == 0) {
        #pragma unroll
        for (int k = 0; k < MM; ++k) {
            red[2*k][iy]     = ar[k];
            red[2*k + 1][iy] = ai[k];
        }
    }
    __syncthreads();
    if (half == 1) {
        #pragma unroll
        for (int ky = 0; ky < MM; ++ky) {
            float2 val;
            val.x = ar[ky] + red[2*ky][iy];
            val.y = ai[ky] + red[2*ky + 1][iy];
            size_t o = ((((size_t)b * MM + ky) * DV + c) * SS + iy) * 2;
            *(float2*)&A[o] = val;
        }
    }
}

// ---------- iy-DFT of A + channel mix -> F (pre-scaled), fused (was 2 kernels)
// grid = (b*MM+ky)*4 + mg (768 blocks). Phase 1: thread = (c, iy-chunk of 32),
// 6 modes via register phasors + 8-lane shfl reduce -> LDS FinS[c][6].
// Phase 2: thread = (o, mode ch<6): out[o][m] = sum_i FinS[i][m] * W[i][o].
__global__ __launch_bounds__(256, 4) void k_cm(const float* __restrict__ A,
        const float* __restrict__ w1r, const float* __restrict__ w1i,
        const float* __restrict__ w2r, const float* __restrict__ w2i,
        float* __restrict__ F, int l)
{
    __shared__ float FinS[DV][6][2];
    int blk = blockIdx.x;
    int mg = blk & 3;
    int bk = blk >> 2;                       // b*MM + ky
    int ky = bk % MM;
    int tid = threadIdx.x;
    int c = tid >> 3, ch = tid & 7;
    int iy0 = ch * 32;

    const float2* Ap = (const float2*)(A + ((size_t)bk * DV + c) * SS * 2);

    float fr[6], fi[6], pc[6], ps[6], sc[6], ssn[6];
    #pragma unroll
    for (int k = 0; k < 6; ++k) {
        int m = mg * 6 + k;
        int f = (m < MM) ? m : (232 + m);    // 244..255 for m >= 12
        float s, cc;
        sincosf(TWO_PI_N * (float)f, &s, &cc);
        sc[k] = cc; ssn[k] = s;
        sincosf(TWO_PI_N * (float)((f * iy0) & 255), &s, &cc);
        pc[k] = cc; ps[k] = s;
        fr[k] = fi[k] = 0.f;
    }
    #pragma unroll 4
    for (int i = 0; i < 32; ++i) {
        float2 a = Ap[iy0 + i];
        #pragma unroll
        for (int k = 0; k < 6; ++k) {
            fr[k] += a.x * pc[k] + a.y * ps[k];   // A * e^{-i th}
            fi[k] += a.y * pc[k] - a.x * ps[k];
            float np = pc[k] * sc[k] - ps[k] * ssn[k];
            float nq = pc[k] * ssn[k] + ps[k] * sc[k];
            pc[k] = np; ps[k] = nq;
        }
    }
    #pragma unroll
    for (int m = 1; m < 8; m <<= 1) {
        #pragma unroll
        for (int k = 0; k < 6; ++k) {
            fr[k] += __shfl_xor(fr[k], m, 64);
            fi[k] += __shfl_xor(fi[k], m, 64);
        }
    }
    #pragma unroll
    for (int k = 0; k < 6; ++k) {
        if (ch == k) { FinS[c][k][0] = fr[k]; FinS[c][k][1] = fi[k]; }
    }
    __syncthreads();

    // phase 2: channel mix for this block's 6 modes (mode-diagonal)
    if (ch < 6) {
        int o = c;
        int m = mg * 6 + ch;
        const float* Wr; const float* Wi; int xm;
        if (m < MM) { Wr = w1r; Wi = w1i; xm = m; }
        else        { Wr = w2r; Wi = w2i; xm = m - MM; }
        float scale = ((ky == 0) ? 1.0f : 2.0f) * (1.0f / 65536.0f);
        float orr = 0.f, oii = 0.f;
        #pragma unroll 4
        for (int i = 0; i < DV; ++i) {
            float gr = FinS[i][ch][0], gi = FinS[i][ch][1];
            size_t wi = ((size_t)(l * DV + i) * DV + o) * (MM * MM) + xm * MM + ky;
            float wr = Wr[wi], wim = Wi[wi];
            orr += gr * wr - gi * wim;
            oii += gr * wim + gi * wr;
        }
        size_t off = (((size_t)bk * DV + o) * MK + m) * 2;
        F[off] = orr * scale; F[off + 1] = oii * scale;
    }
}

// -------------------- inverse iy-DFT: F -> g[b][iy][ky][co][2]
__global__ __launch_bounds__(384) void k_inv1(const float* __restrict__ F,
        float* __restrict__ g)
{
    __shared__ float itw[MK * 2];
    int tid = threadIdx.x;
    int b = blockIdx.x >> 8, iy = blockIdx.x & 255;
    if (tid < MK) {
        int f = (tid < MM) ? tid : (232 + tid);
        float ang = TWO_PI_N * (float)((f * iy) & 255);
        float s, c; sincosf(ang, &s, &c);
        itw[2 * tid] = c; itw[2 * tid + 1] = s;
    }
    __syncthreads();

    int ky = tid >> 5, co = tid & 31;
    const float2* Fp = (const float2*)(F + ((((size_t)b * MM + ky) * DV + co) * MK) * 2);
    float gr = 0.f, gi = 0.f;
    #pragma unroll
    for (int m = 0; m < MK; ++m) {
        float2 fv = Fp[m];
        float ic = itw[2 * m], is = itw[2 * m + 1];
        gr += fv.x * ic - fv.y * is;
        gi += fv.x * is + fv.y * ic;
    }
    size_t o = (((size_t)(b * SS + iy)) * MM + ky) * (DV * 2) + 2 * co;
    g[o] = gr; g[o + 1] = gi;
}

// ----------------- pointwise: h = relu(conv1x1(h) + invDFT(F)), in place.
// grid = NB*128; block = 2 rows x 2 j-halves, one wave per (row, j-half),
// 2 px/thread (float2): acc[32] = 64 VGPR -> ~2x resident waves vs float4.
// Spectral twiddles from tw2 table: one coalesced float4 per ky (L1-hot).
template<int FINAL>
__global__ __launch_bounds__(256, 4) void k_pt(float* __restrict__ h,
        const float* __restrict__ g, const float* __restrict__ wT,
        const float* __restrict__ ws_b, const float* __restrict__ tw2,
        const float* __restrict__ q_w, const float* __restrict__ q_b,
        float* __restrict__ out, int l)
{
    int tid = threadIdx.x;
    int lane = tid & 63;
    int w = __builtin_amdgcn_readfirstlane(tid >> 6);
    int b  = blockIdx.x >> 7;
    int iy = ((blockIdx.x & 127) << 1) + (w >> 1);
    int j0 = ((w & 1) << 7) + (lane << 1);

    float* hb = h + ((size_t)b * DV * SS + iy) * SS + j0;
    const float* wt  = wT + (size_t)l * DV * DV;     // [ci][co], uniform
    const float* wsb = ws_b + (size_t)l * DV;

    float2 acc[DV];
    #pragma unroll
    for (int co = 0; co < DV; ++co) {
        float bv = wsb[co];
        acc[co].x = bv; acc[co].y = bv;
    }

    #pragma unroll 4
    for (int ci = 0; ci < DV; ++ci) {
        float2 hv = *(const float2*)(hb + (size_t)ci * SS * SS);
        const float* wc = wt + ci * DV;              // 32 contiguous s_loads
        #pragma unroll
        for (int co = 0; co < DV; ++co) {
            float wv = wc[co];
            acc[co].x += wv * hv.x; acc[co].y += wv * hv.y;
        }
    }

    const float* gp = g + ((size_t)(b * SS + iy)) * (MM * DV * 2);  // uniform
    #pragma unroll 2
    for (int ky = 0; ky < MM; ++ky) {
        float4 t4 = *(const float4*)(tw2 + ((size_t)ky * SS + j0) * 2);
        // t4 = (cos j0, sin j0, cos j0+1, sin j0+1) for e^{+i 2pi ky j/256}
        const float* Gk = gp + ky * (DV * 2);        // 64 contiguous s_loads
        #pragma unroll
        for (int co = 0; co < DV; ++co) {
            float gr = Gk[2 * co], gi = Gk[2 * co + 1];
            acc[co].x += gr * t4.x - gi * t4.y;
            acc[co].y += gr * t4.z - gi * t4.w;
        }
    }

    if (FINAL) {
        float qb = q_b[0];
        float2 o2; o2.x = qb; o2.y = qb;
        #pragma unroll
        for (int co = 0; co < DV; ++co) {
            float qv = q_w[co];
            o2.x += qv * acc[co].x; o2.y += qv * acc[co].y;
        }
        *(float2*)(out + ((size_t)(b * SS + iy)) * SS + j0) = o2;
    } else {
        #pragma unroll
        for (int co = 0; co < DV; ++co) {
            float2 v;
            v.x = fmaxf(acc[co].x, 0.f); v.y = fmaxf(acc[co].y, 0.f);
            *(float2*)(hb + (size_t)co * SS * SS) = v;
        }
    }
}

extern "C" void kernel_launch(void* const* d_in, const int* in_sizes, int n_in,
                              void* d_out, int out_size, void* d_ws, size_t ws_size,
                              hipStream_t stream)
{
    const float* x    = (const float*)d_in[0];
    const float* p_w  = (const float*)d_in[1];
    const float* p_b  = (const float*)d_in[2];
    const float* ws_w = (const float*)d_in[3];
    const float* ws_b = (const float*)d_in[4];
    const float* w1r  = (const float*)d_in[5];
    const float* w1i  = (const float*)d_in[6];
    const float* w2r  = (const float*)d_in[7];
    const float* w2i  = (const float*)d_in[8];
    const float* q_w  = (const float*)d_in[9];
    const float* q_b  = (const float*)d_in[10];
    float* out = (float*)d_out;

    float* h   = (float*)d_ws;
    float* A   = h   + (size_t)NB * DV * SS * SS;
    float* F   = A   + (size_t)NB * MM * DV * SS * 2;
    float* g   = F   + (size_t)NB * MM * DV * MK * 2;
    float* twT = g   + (size_t)NB * SS * MM * DV * 2;
    float* wT  = twT + (size_t)SS * MM * 2;
    float* tw2 = wT  + (size_t)LL * DV * DV;

    dim3 blk(256);
    k_prep<<<1, blk, 0, stream>>>(ws_w, twT, wT, tw2);
    k_lift<<<NB * 64, blk, 0, stream>>>(x, p_w, p_b, h);
    for (int l = 0; l < LL; ++l) {
        k_rowdft<<<NB * DV, dim3(512), 0, stream>>>(h, twT, A);
        k_cm<<<NB * MM * 4, blk, 0, stream>>>(A, w1r, w1i, w2r, w2i, F, l);
        k_inv1<<<NB * SS, dim3(384), 0, stream>>>(F, g);
        if (l < LL - 1)
            k_pt<0><<<NB * 128, blk, 0, stream>>>(h, g, wT, ws_b, tw2,
                                                  nullptr, nullptr, nullptr, l);
        else
            k_pt<1><<<NB * 128, blk, 0, stream>>>(h, g, wT, ws_b, tw2,
                                                  q_w, q_b, out, l);
    }
}

// Round 11
// 708.261 us; speedup vs baseline: 1.5332x; 1.0413x over previous
//
#include <hip/hip_runtime.h>
#include <math.h>

#define NB 16    // batch
#define SS 256   // spatial size (H = W = 256)
#define DV 32    // channels
#define MM 12    // w-dim (j) modes kept
#define MK 24    // h-dim (iy) modes kept (0..11 and 244..255)
#define LL 4     // layers
#define TWO_PI_N 0.024543692606170259679f   // 2*pi/256
#define TSTR 65  // LDS tile row stride (floats): 65 % 32 = 1 -> conflict-free b32

// Workspace (floats):
//   h   : [NB][DV][SS][SS]            134 MB, in-place per layer
//   A   : [NB][MM][DV][SS(iy)][2]     12.6 MB  (row-DFT of h)
//   F   : [NB][ky:MM][m:MK][co:DV][2]  1.2 MB  (mixed spectral coeffs, pre-scaled)
//   g   : [NB][SS(iy)][MM][DV][2]     12.6 MB  (per-row spectral coeffs)
//   twT : [SS][MM][2]                  24 KB   (cos, -sin) of 2*pi*ky*j/256  (fwd DFT)
//   wT  : [LL][ci][co]                 16 KB   (transposed conv weights)
//   tw2 : [MM][SS][2]                  24 KB   (cos, +sin)  (inverse j-DFT, coalesced)

// --------------------------------------------- setup: tables + weight^T
__global__ __launch_bounds__(256) void k_prep(const float* __restrict__ ws_w,
        float* __restrict__ twT, float* __restrict__ wT, float* __restrict__ tw2)
{
    int j = threadIdx.x;
    #pragma unroll
    for (int k = 0; k < MM; ++k) {
        float ang = TWO_PI_N * (float)((k * j) & 255);
        float s, c; sincosf(ang, &s, &c);
        twT[j * (MM * 2) + 2 * k]     = c;
        twT[j * (MM * 2) + 2 * k + 1] = -s;
        tw2[(k * SS + j) * 2]     = c;
        tw2[(k * SS + j) * 2 + 1] = s;
    }
    for (int idx = threadIdx.x; idx < LL * DV * DV; idx += 256) {
        int l = idx >> 10, rem = idx & 1023, co = rem >> 5, ci = rem & 31;
        wT[(l * DV + ci) * DV + co] = ws_w[(l * DV + co) * DV + ci];
    }
}

// ---------------------------------------------------------------- lifting
// grid = NB*64; block = 4 rows, one wave per row, 4 px/thread (float4).
__global__ __launch_bounds__(256) void k_lift(const float* __restrict__ x,
        const float* __restrict__ p_w, const float* __restrict__ p_b,
        float* __restrict__ h)
{
    int tid = threadIdx.x;
    int lane = tid & 63;
    int w = __builtin_amdgcn_readfirstlane(tid >> 6);
    int b  = blockIdx.x >> 6;
    int iy = ((blockIdx.x & 63) << 2) + w;
    int j0 = lane << 2;

    float4 xv = *(const float4*)(x + ((size_t)(b * SS + iy)) * SS + j0);
    float gy = -1.f + 2.f * (float)iy * (1.f / 255.f);
    float4 gx;
    gx.x = -1.f + 2.f * (float)j0 * (1.f / 255.f);
    gx.y = gx.x + 2.f / 255.f; gx.z = gx.y + 2.f / 255.f; gx.w = gx.z + 2.f / 255.f;

    float* hb = h + ((size_t)b * DV * SS + iy) * SS + j0;
    #pragma unroll
    for (int c = 0; c < DV; ++c) {
        float w0 = p_w[3*c], w1 = p_w[3*c+1], w2 = p_w[3*c+2], bb = p_b[c];
        float4 v;
        v.x = w0 * xv.x + w1 * gy + w2 * gx.x + bb;
        v.y = w0 * xv.y + w1 * gy + w2 * gx.y + bb;
        v.z = w0 * xv.z + w1 * gy + w2 * gx.z + bb;
        v.w = w0 * xv.w + w1 * gy + w2 * gx.w + bb;
        *(float4*)(hb + (size_t)c * SS * SS) = v;
    }
}

// ------------------------------------------------- forward row (j) DFT, 12 modes
// block = (b,c); 512 threads. j processed in 4 tiles of 64:
//   stage: 256iy x 64j -> LDS, fully coalesced float4 global loads
//          (4 x 256B row-segments per wave-instr vs 64-line gather before)
//   compute: thread = (iy = tid&255, half = tid>>8); j wave-uniform -> s_load
//          twiddles; LDS reads b32 at row stride 65 -> conflict-free.
// smem reused for the cross-half reduction at the end.
__global__ __launch_bounds__(512, 4) void k_rowdft(const float* __restrict__ h,
        const float* __restrict__ twT, float* __restrict__ A)
{
    __shared__ float smem[SS * TSTR];   // 66.6 KB; 2 blocks/CU
    int tid = threadIdx.x;
    int iy = tid & 255;
    int half = __builtin_amdgcn_readfirstlane(tid >> 8);
    int b = blockIdx.x >> 5, c = blockIdx.x & 31;
    const float* hrow = h + (size_t)blockIdx.x * SS * SS;   // [iy][j] of (b,c)

    float ar[MM], ai[MM];
    #pragma unroll
    for (int k = 0; k < MM; ++k) { ar[k] = 0.f; ai[k] = 0.f; }

    for (int t = 0; t < 4; ++t) {
        int jb = t * 64;
        __syncthreads();                 // smem free (prev tile / prev phase)
        #pragma unroll
        for (int k = 0; k < 8; ++k) {
            int idx = tid + k * 512;     // 0..4095
            int row = idx >> 4, col4 = idx & 15;
            float4 v = *(const float4*)(hrow + (size_t)row * SS + jb + col4 * 4);
            float* d = &smem[row * TSTR + col4 * 4];
            d[0] = v.x; d[1] = v.y; d[2] = v.z; d[3] = v.w;
        }
        __syncthreads();
        const float* rp = &smem[iy * TSTR + half * 32];
        #pragma unroll
        for (int jq = 0; jq < 8; ++jq) {
            #pragma unroll
            for (int u = 0; u < 4; ++u) {
                float v = rp[jq * 4 + u];
                const float* twj = twT + (size_t)(jb + half * 32 + jq * 4 + u)
                                         * (MM * 2);      // wave-uniform
                #pragma unroll
                for (int k = 0; k < 6; ++k) {
                    ar[2*k]   += v * twj[4*k];
                    ai[2*k]   += v * twj[4*k + 1];
                    ar[2*k+1] += v * twj[4*k + 2];
                    ai[2*k+1] += v * twj[4*k + 3];
                }
            }
        }
    }

    __syncthreads();                     // reuse smem as red[24][256]
    if (half == 0) {
        #pragma unroll
        for (int k = 0; k < MM; ++k) {
            smem[(2*k) * SS + iy]     = ar[k];
            smem[(2*k + 1) * SS + iy] = ai[k];
        }
    }
    __syncthreads();
    if (half == 1) {
        #pragma unroll
        for (int ky = 0; ky < MM; ++ky) {
            float2 val;
            val.x = ar[ky] + smem[(2*ky) * SS + iy];
            val.y = ai[ky] + smem[(2*ky + 1) * SS + iy];
            size_t o = ((((size_t)b * MM + ky) * DV + c) * SS + iy) * 2;
            *(float2*)&A[o] = val;
        }
    }
}

// ---------- iy-DFT of A + channel mix -> F (pre-scaled), fused
// grid = (b*MM+ky)*4 + mg (768 blocks). Phase 1: thread = (c, iy-chunk of 32),
// 6 modes via register phasors + 8-lane shfl reduce -> LDS FinS[c][6].
// Phase 2: thread = (o, mode ch<6): F[ky][m][o] = sum_i FinS[i][m] * W[i][o].
__global__ __launch_bounds__(256, 4) void k_cm(const float* __restrict__ A,
        const float* __restrict__ w1r, const float* __restrict__ w1i,
        const float* __restrict__ w2r, const float* __restrict__ w2i,
        float* __restrict__ F, int l)
{
    __shared__ float FinS[DV][6][2];
    int blk = blockIdx.x;
    int mg = blk & 3;
    int bk = blk >> 2;                       // b*MM + ky
    int ky = bk % MM;
    int tid = threadIdx.x;
    int c = tid >> 3, ch = tid & 7;
    int iy0 = ch * 32;

    const float2* Ap = (const float2*)(A + ((size_t)bk * DV + c) * SS * 2);

    float fr[6], fi[6], pc[6], ps[6], sc[6], ssn[6];
    #pragma unroll
    for (int k = 0; k < 6; ++k) {
        int m = mg * 6 + k;
        int f = (m < MM) ? m : (232 + m);    // 244..255 for m >= 12
        float s, cc;
        sincosf(TWO_PI_N * (float)f, &s, &cc);
        sc[k] = cc; ssn[k] = s;
        sincosf(TWO_PI_N * (float)((f * iy0) & 255), &s, &cc);
        pc[k] = cc; ps[k] = s;
        fr[k] = fi[k] = 0.f;
    }
    #pragma unroll 4
    for (int i = 0; i < 32; ++i) {
        float2 a = Ap[iy0 + i];
        #pragma unroll
        for (int k = 0; k < 6; ++k) {
            fr[k] += a.x * pc[k] + a.y * ps[k];   // A * e^{-i th}
            fi[k] += a.y * pc[k] - a.x * ps[k];
            float np = pc[k] * sc[k] - ps[k] * ssn[k];
            float nq = pc[k] * ssn[k] + ps[k] * sc[k];
            pc[k] = np; ps[k] = nq;
        }
    }
    #pragma unroll
    for (int m = 1; m < 8; m <<= 1) {
        #pragma unroll
        for (int k = 0; k < 6; ++k) {
            fr[k] += __shfl_xor(fr[k], m, 64);
            fi[k] += __shfl_xor(fi[k], m, 64);
        }
    }
    #pragma unroll
    for (int k = 0; k < 6; ++k) {
        if (ch == k) { FinS[c][k][0] = fr[k]; FinS[c][k][1] = fi[k]; }
    }
    __syncthreads();

    // phase 2: channel mix for this block's 6 modes (mode-diagonal)
    if (ch < 6) {
        int o = c;
        int m = mg * 6 + ch;
        const float* Wr; const float* Wi; int xm;
        if (m < MM) { Wr = w1r; Wi = w1i; xm = m; }
        else        { Wr = w2r; Wi = w2i; xm = m - MM; }
        float scale = ((ky == 0) ? 1.0f : 2.0f) * (1.0f / 65536.0f);
        float orr = 0.f, oii = 0.f;
        #pragma unroll 4
        for (int i = 0; i < DV; ++i) {
            float gr = FinS[i][ch][0], gi = FinS[i][ch][1];
            size_t wi = ((size_t)(l * DV + i) * DV + o) * (MM * MM) + xm * MM + ky;
            float wr = Wr[wi], wim = Wi[wi];
            orr += gr * wr - gi * wim;
            oii += gr * wim + gi * wr;
        }
        size_t off = (((size_t)bk * MK + m) * DV + o) * 2;   // [ky][m][co]
        F[off] = orr * scale; F[off + 1] = oii * scale;
    }
}

// -------------------- inverse iy-DFT: F -> g[b][iy][ky][co][2]
// F layout [b][ky][m][co][2] -> inner m-loop loads are lane-contiguous.
__global__ __launch_bounds__(384) void k_inv1(const float* __restrict__ F,
        float* __restrict__ g)
{
    __shared__ float itw[MK * 2];
    int tid = threadIdx.x;
    int b = blockIdx.x >> 8, iy = blockIdx.x & 255;
    if (tid < MK) {
        int f = (tid < MM) ? tid : (232 + tid);
        float ang = TWO_PI_N * (float)((f * iy) & 255);
        float s, c; sincosf(ang, &s, &c);
        itw[2 * tid] = c; itw[2 * tid + 1] = s;
    }
    __syncthreads();

    int ky = tid >> 5, co = tid & 31;
    const float* Fp = F + ((size_t)(b * MM + ky) * MK) * (DV * 2) + 2 * co;
    float gr = 0.f, gi = 0.f;
    #pragma unroll
    for (int m = 0; m < MK; ++m) {
        float2 fv = *(const float2*)(Fp + (size_t)m * (DV * 2));  // coalesced
        float ic = itw[2 * m], is = itw[2 * m + 1];
        gr += fv.x * ic - fv.y * is;
        gi += fv.x * is + fv.y * ic;
    }
    size_t o = (((size_t)(b * SS + iy)) * MM + ky) * (DV * 2) + 2 * co;
    g[o] = gr; g[o + 1] = gi;
}

// ----------------- pointwise: h = relu(conv1x1(h) + invDFT(F)), in place.
// grid = NB*128; block = 2 rows x 2 j-halves, one wave per (row, j-half),
// 2 px/thread (float2). (unchanged from round 10 — proven)
template<int FINAL>
__global__ __launch_bounds__(256, 4) void k_pt(float* __restrict__ h,
        const float* __restrict__ g, const float* __restrict__ wT,
        const float* __restrict__ ws_b, const float* __restrict__ tw2,
        const float* __restrict__ q_w, const float* __restrict__ q_b,
        float* __restrict__ out, int l)
{
    int tid = threadIdx.x;
    int lane = tid & 63;
    int w = __builtin_amdgcn_readfirstlane(tid >> 6);
    int b  = blockIdx.x >> 7;
    int iy = ((blockIdx.x & 127) << 1) + (w >> 1);
    int j0 = ((w & 1) << 7) + (lane << 1);

    float* hb = h + ((size_t)b * DV * SS + iy) * SS + j0;
    const float* wt  = wT + (size_t)l * DV * DV;     // [ci][co], uniform
    const float* wsb = ws_b + (size_t)l * DV;

    float2 acc[DV];
    #pragma unroll
    for (int co = 0; co < DV; ++co) {
        float bv = wsb[co];
        acc[co].x = bv; acc[co].y = bv;
    }

    #pragma unroll 4
    for (int ci = 0; ci < DV; ++ci) {
        float2 hv = *(const float2*)(hb + (size_t)ci * SS * SS);
        const float* wc = wt + ci * DV;              // 32 contiguous s_loads
        #pragma unroll
        for (int co = 0; co < DV; ++co) {
            float wv = wc[co];
            acc[co].x += wv * hv.x; acc[co].y += wv * hv.y;
        }
    }

    const float* gp = g + ((size_t)(b * SS + iy)) * (MM * DV * 2);  // uniform
    #pragma unroll 2
    for (int ky = 0; ky < MM; ++ky) {
        float4 t4 = *(const float4*)(tw2 + ((size_t)ky * SS + j0) * 2);
        const float* Gk = gp + ky * (DV * 2);        // 64 contiguous s_loads
        #pragma unroll
        for (int co = 0; co < DV; ++co) {
            float gr = Gk[2 * co], gi = Gk[2 * co + 1];
            acc[co].x += gr * t4.x - gi * t4.y;
            acc[co].y += gr * t4.z - gi * t4.w;
        }
    }

    if (FINAL) {
        float qb = q_b[0];
        float2 o2; o2.x = qb; o2.y = qb;
        #pragma unroll
        for (int co = 0; co < DV; ++co) {
            float qv = q_w[co];
            o2.x += qv * acc[co].x; o2.y += qv * acc[co].y;
        }
        *(float2*)(out + ((size_t)(b * SS + iy)) * SS + j0) = o2;
    } else {
        #pragma unroll
        for (int co = 0; co < DV; ++co) {
            float2 v;
            v.x = fmaxf(acc[co].x, 0.f); v.y = fmaxf(acc[co].y, 0.f);
            *(float2*)(hb + (size_t)co * SS * SS) = v;
        }
    }
}

extern "C" void kernel_launch(void* const* d_in, const int* in_sizes, int n_in,
                              void* d_out, int out_size, void* d_ws, size_t ws_size,
                              hipStream_t stream)
{
    const float* x    = (const float*)d_in[0];
    const float* p_w  = (const float*)d_in[1];
    const float* p_b  = (const float*)d_in[2];
    const float* ws_w = (const float*)d_in[3];
    const float* ws_b = (const float*)d_in[4];
    const float* w1r  = (const float*)d_in[5];
    const float* w1i  = (const float*)d_in[6];
    const float* w2r  = (const float*)d_in[7];
    const float* w2i  = (const float*)d_in[8];
    const float* q_w  = (const float*)d_in[9];
    const float* q_b  = (const float*)d_in[10];
    float* out = (float*)d_out;

    float* h   = (float*)d_ws;
    float* A   = h   + (size_t)NB * DV * SS * SS;
    float* F   = A   + (size_t)NB * MM * DV * SS * 2;
    float* g   = F   + (size_t)NB * MM * MK * DV * 2;
    float* twT = g   + (size_t)NB * SS * MM * DV * 2;
    float* wT  = twT + (size_t)SS * MM * 2;
    float* tw2 = wT  + (size_t)LL * DV * DV;

    dim3 blk(256);
    k_prep<<<1, blk, 0, stream>>>(ws_w, twT, wT, tw2);
    k_lift<<<NB * 64, blk, 0, stream>>>(x, p_w, p_b, h);
    for (int l = 0; l < LL; ++l) {
        k_rowdft<<<NB * DV, dim3(512), 0, stream>>>(h, twT, A);
        k_cm<<<NB * MM * 4, blk, 0, stream>>>(A, w1r, w1i, w2r, w2i, F, l);
        k_inv1<<<NB * SS, dim3(384), 0, stream>>>(F, g);
        if (l < LL - 1)
            k_pt<0><<<NB * 128, blk, 0, stream>>>(h, g, wT, ws_b, tw2,
                                                  nullptr, nullptr, nullptr, l);
        else
            k_pt<1><<<NB * 128, blk, 0, stream>>>(h, g, wT, ws_b, tw2,
                                                  q_w, q_b, out, l);
    }
}